// Round 9
// baseline (75.805 us; speedup 1.0000x reference)
//
#include <hip/hip_runtime.h>
#include <math.h>

// Contour-to-distance-map, round 9.
// R8 accounting: winding ~32us vs ~6us VALU floor; op-removals pay 1:1 but a
// ~130cy/step CONSTANT remains. Theory: the per-step __any branch is a TAKEN
// s_cbranch over the inline slow path -> 2 I-fetch redirects/step (~40-80cy)
// + 10 tiny scheduling regions per unroll group; plus per-load (n<N?:0)
// cselects on the CU-shared SALU pipe.
// Changes:
//   (a) group-of-5 batching: diffs are (vertex,pixel)-only (not chained);
//       compute 5 diffs/d2/crz straight-line, ONE __any(min|crz|<CTHR) per
//       group (10x fewer branches). Slow path redoes the group's corrections
//       (unflagged lanes add exactly 0 -> no masking).
//   (b) pre-wrapped ext contour in d_ws via prep kernel: ext[n]=n<N?c[n]:c[0]
//       -> plain scalar loads, no cselect.
//   (c) 4-way edge split/wave (one chain; ILP from the 5 indep group lanes).

#define INV_2PI 0.15915494309189535f
#define TWO_PI  6.28318530717958648f
#define PI_F  3.14159265358979323846f
#define HPI_F 1.57079632679489662f
#define KK2   200000.0f               // 2*k
#define CTHR  9e-5f                   // |crz| below this -> exact correction
#define G     5                       // group size (edges per branch)

__device__ __forceinline__ float atan01(float q) {
    // A&S 4.4.49: atan(q), q in [0,1], |err| <= 1e-5
    const float z = q * q;
    float p = fmaf(z,  0.0208351f, -0.0851330f);
    p = fmaf(z, p,  0.1801410f);
    p = fmaf(z, p, -0.3302995f);
    p = fmaf(z, p,  0.9998660f);
    return q * p;
}

__global__ void prep_kernel(const float2* __restrict__ contour,
                            float2* __restrict__ ext, int N, int L) {
    const int t = blockIdx.x * blockDim.x + threadIdx.x;
    if (t < L) ext[t] = contour[(t < N) ? t : 0];
}

__global__ void __launch_bounds__(256, 4)
winding_kernel(const float2* __restrict__ ext, int Q, int NG, int S,
               float invS, float* __restrict__ out, float* __restrict__ bmax) {
    __shared__ float s_w[4][64];
    __shared__ float s_m[4][64];

    const int tid  = threadIdx.x;
    const int lane = tid & 63;
    const int wid  = __builtin_amdgcn_readfirstlane(tid >> 6); // force SGPR

    const int total = S * S;
    const int p = blockIdx.x * 64 + lane;     // 64 pixels per block
    const bool valid = (p < total);

    const int i = p / S, j = p - i * S;
    const float px = (float)i * invS, py = (float)j * invS;

    const int a0 = wid * Q;                   // scalar: this wave's edge base

    // carried prev-vertex diff
    float2 v0 = ext[a0];
    float dxp = v0.x - px;
    float dyp = v0.y - py;
    float minn = fmaf(dxp, dxp, dyp * dyp);
    float wcorr = 0.0f;
    int   wind = 0;

    for (int g = 0; g < NG; ++g) {
        const int kbase = a0 + g * G;         // scalar

        float dxa[G + 1], dya[G + 1], crza[G], d2a[G];
        dxa[0] = dxp; dya[0] = dyp;

        #pragma unroll
        for (int q = 1; q <= G; ++q) {        // 5 scalar loads, straight-line
            const float2 v = ext[kbase + q];
            dxa[q] = v.x - px;
            dya[q] = v.y - py;
        }
        #pragma unroll
        for (int q = 0; q < G; ++q) {
            d2a[q]  = fmaf(dxa[q + 1], dxa[q + 1], dya[q + 1] * dya[q + 1]);
            crza[q] = fmaf(dxa[q], dya[q + 1], -(dya[q] * dxa[q + 1]));
        }
        // min-dist tree
        minn = fminf(minn, fminf(fminf(fminf(d2a[0], d2a[1]),
                                       fminf(d2a[2], d2a[3])), d2a[4]));
        // half-open ray crossings (same predicates as R8)
        #pragma unroll
        for (int q = 0; q < G; ++q) {
            const bool pc = (dya[q]     <= 0.0f);
            const bool pn = (dya[q + 1] <= 0.0f);
            const int up = (pc & !pn & (crza[q] > 0.0f)) ? 1 : 0;
            const int dn = (!pc & pn & (crza[q] < 0.0f)) ? 1 : 0;
            wind += up - dn;
        }
        // one branch per group
        const float amin = fminf(fminf(fminf(fabsf(crza[0]), fabsf(crza[1])),
                                       fminf(fabsf(crza[2]), fabsf(crza[3]))),
                                 fabsf(crza[4]));
        if (__any(amin < CTHR)) {             // rare: exact tanh-weight corr
            #pragma unroll
            for (int q = 0; q < G; ++q) {
                const float crz = crza[q];
                const float dot = fmaf(dxa[q], dxa[q + 1],
                                       dya[q] * dya[q + 1]);
                const float ay = fabsf(crz);
                const float ax = fabsf(dot);
                const float mn = fminf(ax, ay);
                const float mx = fmaxf(ax, ay);
                const float qq = mn * __builtin_amdgcn_rcpf(fmaxf(mx, 1e-30f));
                float an = atan01(qq);
                an = (ay > ax)    ? (HPI_F - an) : an;
                an = (dot < 0.0f) ? (PI_F - an)  : an;
                const float e = __expf(ay * -KK2);
                const float t = (1.0f - e) * __builtin_amdgcn_rcpf(1.0f + e);
                // (1-t)==0 exactly for |crz|>=CTHR lanes -> no mask needed
                wcorr = fmaf(1.0f - t, copysignf(an, -crz), wcorr);
            }
        }
        dxp = dxa[G]; dyp = dya[G];
    }

    // w_partial = -2*pi*wind - wcorr
    s_w[wid][lane] = fmaf(-TWO_PI, (float)wind, -wcorr);
    s_m[wid][lane] = minn;
    __syncthreads();

    if (wid == 0) {
        const float wt = (s_w[0][lane] + s_w[1][lane]) +
                         (s_w[2][lane] + s_w[3][lane]);
        const float mt = fminf(fminf(s_m[0][lane], s_m[1][lane]),
                               fminf(s_m[2][lane], s_m[3][lane]));
        float prod = valid ? (wt * INV_2PI) * __builtin_amdgcn_sqrtf(mt)
                           : -INFINITY;
        if (valid) out[p] = prod;

        float v = prod;
        #pragma unroll
        for (int off = 32; off >= 1; off >>= 1)
            v = fmaxf(v, __shfl_down(v, off, 64));
        if (lane == 0) bmax[blockIdx.x] = v;
    }
}

__global__ void __launch_bounds__(256)
normalize_kernel(float4* __restrict__ out4, const float* __restrict__ bmax,
                 int nmax, int total4) {
    const int tid  = threadIdx.x;
    const int lane = tid & 63;
    const int wid  = tid >> 6;

    float m = -INFINITY;
    for (int t = tid; t < nmax; t += 256) m = fmaxf(m, bmax[t]);
    #pragma unroll
    for (int off = 32; off >= 1; off >>= 1)
        m = fmaxf(m, __shfl_down(m, off, 64));
    __shared__ float sm[4];
    if (lane == 0) sm[wid] = m;
    __syncthreads();
    m = fmaxf(fmaxf(sm[0], sm[1]), fmaxf(sm[2], sm[3]));
    const float inv = 1.0f / m;

    const int idx = blockIdx.x * 256 + tid;
    if (idx < total4) {
        float4 v = out4[idx];
        v.x *= inv; v.y *= inv; v.z *= inv; v.w *= inv;
        out4[idx] = v;
    }
}

extern "C" void kernel_launch(void* const* d_in, const int* in_sizes, int n_in,
                              void* d_out, int out_size, void* d_ws, size_t ws_size,
                              hipStream_t stream) {
    const float2* contour = (const float2*)d_in[0];
    const int N = in_sizes[0] / 2;                       // 200
    const int S = (int)(sqrt((double)out_size) + 0.5);   // 384
    const float invS = 1.0f / (float)S;
    float* out  = (float*)d_out;
    float* bmax = (float*)d_ws;                          // 2304 floats
    float2* ext = (float2*)((char*)d_ws + 16384);        // wrapped contour

    // per-wave edge count Q (4-way split), group-padded; pad edges are
    // c0->c0 (crz==0 exactly -> counted 0, slow path exact-0 correction)
    const int Q0 = (N + 3) / 4;
    const int NG = (Q0 + G - 1) / G;
    const int Q  = NG * G;                               // 50 for N=200
    const int L  = 3 * Q0 + Q + 1;                       // max index + 1

    prep_kernel<<<(L + 255) / 256, 256, 0, stream>>>(contour, ext, N, L);

    const int total   = S * S;
    const int wblocks = (total + 63) / 64;               // 2304
    winding_kernel<<<wblocks, 256, 0, stream>>>(ext, Q, NG, S, invS, out, bmax);

    const int total4  = total / 4;
    const int nblocks = (total4 + 255) / 256;            // 144
    normalize_kernel<<<nblocks, 256, 0, stream>>>((float4*)out, bmax,
                                                  wblocks, total4);
}